// Round 9
// baseline (172.739 us; speedup 1.0000x reference)
//
#include <hip/hip_runtime.h>
#include <math.h>

// MinibatchDiscrimination: B=512, IN=512, OUT=100, K=5
//   M = x @ T.view(512,500);  out[j,o] = sum_i exp(-sum_k|M[i,o,k]-M[j,o,k]|) - 1
//
// R8 post-mortem: three gemm structures all plateau at ~83-85us total; the
// controllable cost is split between dispatch gaps (~5-6us each, measured via
// R5) and gemm pipe-imbalance (R8's s_load gemm ~25us scalar-cache-bound).
//
// This round: ONE regular dispatch. Grid (100 o, 4 jc) x 512 thr.
// Each block computes the full M column for its o in-block (x4 replication
// = 524M FMA = 6.7us VALU-ideal; x comes from per-XCD L2, ~400MB ~12us,
// overlapped), then does pairwise for its 128 j's. No workspace, no
// intermediate kernels, no atomics.
//  - T staged per block as SoA Tl[k][c] scaled by log2(e)
//    (|s*a-s*b| = s|a-b|, s>0  =>  exp(-n) == exp2(-n_scaled));
//    inner-loop T reads are ds_read_b128 wave-broadcast (free-ish).
//  - gemm thread = (i-pair, c-half): 2 i/thread halves the T-read per FMA
//    (LDS 60cyc vs FMA 80cyc per 4c -> VALU-bound, unlike R5/R6);
//    c-half partials merged with one __shfl_xor (partner = adjacent lane).
//  - pairwise: R6-proven; i-loop reads are wave-broadcast.

#define NB    512
#define NIN   512
#define NOUT  100
#define KDIM  5
#define NCOL  500
#define LOG2E 1.44269504088896340736f

__global__ __launch_bounds__(512) void fused_kernel(const float* __restrict__ x,
                                                    const float* __restrict__ T,
                                                    float* __restrict__ out) {
    __shared__ float Tl[KDIM][NB];    // 10 KB  SoA, pre-scaled by log2e
    __shared__ float Ms[NB * 8];      // 16 KB  Ms[i*8+k]
    __shared__ float Pw[4][128];      // 2 KB   i-split partials

    const int o  = blockIdx.x;        // 0..99
    const int jc = blockIdx.y;        // 0..3
    const int t  = threadIdx.x;       // 0..511

    // ---- stage T column (c = t), scaled
    {
        const float* src = T + t * NCOL + o * KDIM;
        #pragma unroll
        for (int k = 0; k < KDIM; ++k)
            Tl[k][t] = src[k] * LOG2E;
    }
    __syncthreads();

    // ---- gemm: thread = (i-pair i0..i0+1, c-half cs)
    {
        const int cs = t & 1;
        const int i0 = t & ~1;                    // == (t>>1)*2
        const float* xr0 = x + i0 * NIN + cs * 256;
        const float* xr1 = xr0 + NIN;

        float acc0[5] = {0.f,0.f,0.f,0.f,0.f};
        float acc1[5] = {0.f,0.f,0.f,0.f,0.f};

        #pragma unroll 2
        for (int c = 0; c < 256; c += 4) {
            const float4 xa = *reinterpret_cast<const float4*>(xr0 + c);
            const float4 xb = *reinterpret_cast<const float4*>(xr1 + c);
            const int cg = cs * 256 + c;
            float4 tk[5];
            #pragma unroll
            for (int k = 0; k < 5; ++k)
                tk[k] = *reinterpret_cast<const float4*>(&Tl[k][cg]);  // broadcast b128
            const float xa_[4] = {xa.x, xa.y, xa.z, xa.w};
            const float xb_[4] = {xb.x, xb.y, xb.z, xb.w};
            #pragma unroll
            for (int q = 0; q < 4; ++q) {
                #pragma unroll
                for (int k = 0; k < 5; ++k) {
                    const float tv = reinterpret_cast<const float*>(&tk[k])[q];
                    acc0[k] = fmaf(xa_[q], tv, acc0[k]);
                    acc1[k] = fmaf(xb_[q], tv, acc1[k]);
                }
            }
        }
        // merge c-halves: partner lane is t^1 (same i-pair, other half)
        #pragma unroll
        for (int k = 0; k < 5; ++k) {
            acc0[k] += __shfl_xor(acc0[k], 1, 64);
            acc1[k] += __shfl_xor(acc1[k], 1, 64);
        }
        if (cs == 0) {
            float* d0 = &Ms[i0 * 8];
            *reinterpret_cast<float4*>(d0)     = make_float4(acc0[0], acc0[1], acc0[2], acc0[3]);
            *reinterpret_cast<float4*>(d0 + 4) = make_float4(acc0[4], 0.f, 0.f, 0.f);
            float* d1 = &Ms[(i0 + 1) * 8];
            *reinterpret_cast<float4*>(d1)     = make_float4(acc1[0], acc1[1], acc1[2], acc1[3]);
            *reinterpret_cast<float4*>(d1 + 4) = make_float4(acc1[4], 0.f, 0.f, 0.f);
        }
    }
    __syncthreads();

    // ---- pairwise: thread = (j, i-quarter); i-reads wave-broadcast
    {
        const int jg = t & 127;
        const int is = t >> 7;                    // 4 i-splits x 128 i
        const int j  = jc * 128 + jg;
        const float* mj = &Ms[j * 8];
        const float jv0 = mj[0], jv1 = mj[1], jv2 = mj[2], jv3 = mj[3], jv4 = mj[4];

        float acc = 0.f;
        const int ib = is * 128;
        #pragma unroll 4
        for (int it = 0; it < 128; ++it) {
            const float* m = &Ms[(ib + it) * 8];
            const float n = fabsf(m[0] - jv0) + fabsf(m[1] - jv1) + fabsf(m[2] - jv2)
                          + fabsf(m[3] - jv3) + fabsf(m[4] - jv4);
            acc += exp2f(-n);                     // pre-scaled -> e^{-norm}
        }
        Pw[is][jg] = acc;
    }
    __syncthreads();

    if (t < 128) {
        const float tot = Pw[0][t] + Pw[1][t] + Pw[2][t] + Pw[3][t] - 1.0f;  // - self
        out[(jc * 128 + t) * NOUT + o] = tot;
    }
}

extern "C" void kernel_launch(void* const* d_in, const int* in_sizes, int n_in,
                              void* d_out, int out_size, void* d_ws, size_t ws_size,
                              hipStream_t stream) {
    const float* x = (const float*)d_in[0];   // [512,512]
    const float* T = (const float*)d_in[1];   // [512,500]
    float* out = (float*)d_out;               // [512,100]

    fused_kernel<<<dim3(NOUT, 4), 512, 0, stream>>>(x, T, out);
}